// Round 9
// baseline (394.485 us; speedup 1.0000x reference)
//
#include <hip/hip_runtime.h>
#include <hip/hip_bf16.h>

// DeepseekV3 MoE: B=2,S=2048 -> n=4096 tokens, H=1024, I=256, E=256, K=8, G=8, TG=4, NS=2
// All inputs f32. Output f32 [4096][1024].

typedef __attribute__((ext_vector_type(4))) float  f32x4;
typedef __attribute__((ext_vector_type(8))) short  bf16x8;
typedef __attribute__((ext_vector_type(4))) short  bf16x4;
typedef __attribute__((ext_vector_type(4))) unsigned short u16x4;

#define DI static __device__ __forceinline__

DI unsigned short f2bf(float f){
  unsigned u = __builtin_bit_cast(unsigned, f);
  return (unsigned short)((u + 0x7FFFu + ((u>>16)&1u)) >> 16); // RNE (inputs finite)
}
DI float bf2f(unsigned short s){
  return __builtin_bit_cast(float, ((unsigned)s)<<16);
}

// ---------------- workspace layout (bytes) ----------------
#define WS_XBF      0u          /* 4096*1024 bf16 = 8,388,608 */
#define WS_HSH      8388608u    /* 4096*512 bf16  = 4,194,304 (shared h, concat s) */
#define WS_HMID     12582912u   /* 32768*256 bf16 = 16,777,216 */
#define WS_WGT      29360128u   /* WgT 1024*256 f32 = 1MB */
#define WS_TOPKI    96468992u   /* 4096*8 int */
#define WS_TOPKW    96600064u   /* 4096*8 f32 */
#define WS_TOKMAP   96731136u   /* 32768 int */
#define WS_WMAP     96862208u   /* 32768 f32 (per-slot router weight) */
#define WS_CNT      96993280u   /* 256 int */
#define WS_CURSOR   96994304u   /* 256 int */
#define WS_ZERO     96995328u   /* 4096 B zeros */
#define WS_OFF      96999424u   /* 257 int */

// ---------------- transpose Wg [256][1024] -> WgT [1024][256] ----------------
__global__ __launch_bounds__(256) void k_wgT(const float* __restrict__ Wg, float* __restrict__ WgT){
  __shared__ float t[64][65];
  const int tid = threadIdx.x;
  const int hx = blockIdx.x * 64;   // h tile (16 blocks)
  const int ex = blockIdx.y * 64;   // e tile (4 blocks)
  #pragma unroll
  for (int k=0;k<16;++k){
    int i = (tid>>6)*16 + k, j = tid&63;
    t[i][j] = Wg[(size_t)(ex+i)*1024 + hx + j];   // coalesced over j
  }
  __syncthreads();
  #pragma unroll
  for (int k=0;k<16;++k){
    int i = (tid>>6)*16 + k, j = tid&63;
    WgT[(size_t)(hx+i)*256 + ex + j] = t[j][i];   // coalesced over j
  }
}

// ---------------- router: logits via coalesced WgT + grouped top-k + softmax; folds x->bf16 ----------------
__global__ __launch_bounds__(256) void k_router(const float* __restrict__ x, const float* __restrict__ WgT,
                                                unsigned short* __restrict__ xbf,
                                                int* __restrict__ topki, float* __restrict__ topkw,
                                                int* __restrict__ cnt){
  __shared__ float xs[8][1024];   // 32KB
  __shared__ float lg[8][256];    // 8KB
  __shared__ float cv[8][32];
  __shared__ int   ce[8][32];
  const int tid = threadIdx.x;
  const int t0  = blockIdx.x * 8;
  { // load x tile + convert to bf16 (folded k_convert)
    const f32x4* xg = (const f32x4*)(x + (size_t)t0*1024);
    f32x4* xs4 = (f32x4*)&xs[0][0];
    u16x4* xb4 = (u16x4*)(xbf + (size_t)t0*1024);
    #pragma unroll
    for (int i=0;i<8;++i){
      f32x4 v = xg[tid + i*256];
      xs4[tid + i*256] = v;
      u16x4 p; p[0]=f2bf(v[0]); p[1]=f2bf(v[1]); p[2]=f2bf(v[2]); p[3]=f2bf(v[3]);
      xb4[tid + i*256] = p;
    }
  }
  __syncthreads();
  { // logits: expert e = tid; WgT reads coalesced (lane = expert); x broadcast from LDS
    f32x4 a4[8];
    #pragma unroll
    for (int t=0;t<8;++t) a4[t] = (f32x4){0.f,0.f,0.f,0.f};
    const float* wc = WgT + tid;
    for (int h4=0; h4<256; ++h4){
      float w0 = wc[(size_t)(h4*4+0)*256];
      float w1 = wc[(size_t)(h4*4+1)*256];
      float w2 = wc[(size_t)(h4*4+2)*256];
      float w3 = wc[(size_t)(h4*4+3)*256];
      f32x4 wv = (f32x4){w0,w1,w2,w3};
      #pragma unroll
      for (int t=0;t<8;++t){
        f32x4 xv = *((const f32x4*)&xs[t][0] + h4);
        a4[t] += wv * xv;
      }
    }
    #pragma unroll
    for (int t=0;t<8;++t){
      double d = ((double)a4[t][0] + (double)a4[t][1]) + ((double)a4[t][2] + (double)a4[t][3]);
      lg[t][tid] = (float)d;
    }
  }
  __syncthreads();
  if (tid < 64){ // per (token, group): top-4 of 32, ties -> lowest index
    int tok = tid>>3, grp = tid&7;
    unsigned mask = 0;
    for (int j=0;j<4;++j){
      float best = -3.4e38f; int bi = 0;
      for (int i=0;i<32;++i){
        float v = lg[tok][grp*32+i];
        if (!((mask>>i)&1u) && v > best){ best=v; bi=i; }
      }
      mask |= 1u<<bi;
      cv[tok][grp*4+j] = best; ce[tok][grp*4+j] = grp*32+bi;
    }
  }
  __syncthreads();
  if (tid < 8){ // per token: top-8 of 32 candidates + softmax
    int tok = tid; unsigned mask=0;
    float vals[8]; int es[8];
    #pragma unroll
    for (int k=0;k<8;++k){
      float best=-3.4e38f; int bp=0;
      for (int p=0;p<32;++p){
        float v = cv[tok][p];
        if (!((mask>>p)&1u) && v > best){ best=v; bp=p; }
      }
      mask|=1u<<bp; vals[k]=best; es[k]=ce[tok][bp];
    }
    float m = vals[0], s=0.f, w[8];
    #pragma unroll
    for (int k=0;k<8;++k){ w[k]=expf(vals[k]-m); s+=w[k]; }
    float inv = 1.f/s;
    #pragma unroll
    for (int k=0;k<8;++k){
      int g=(t0+tok)*8+k;
      topki[g]=es[k]; topkw[g]=w[k]*inv;
      atomicAdd(&cnt[es[k]],1);
    }
  }
}

// ---------------- exclusive scan of 256 counts ----------------
__global__ void k_scan(const int* __restrict__ cnt, int* __restrict__ off){
  __shared__ int s[256];
  int tid=threadIdx.x;
  s[tid]=cnt[tid]; __syncthreads();
  for (int d=1; d<256; d<<=1){
    int v = (tid>=d)? s[tid-d] : 0; __syncthreads();
    s[tid]+=v; __syncthreads();
  }
  off[tid+1]=s[tid]; if(tid==0) off[0]=0;
}

// ---------------- scatter tokens into per-expert slots ----------------
__global__ void k_scatter(const int* __restrict__ topki, const float* __restrict__ topkw,
                          const int* __restrict__ off, int* __restrict__ cursor,
                          int* __restrict__ tokmap, float* __restrict__ wmap){
  int g = blockIdx.x*256 + threadIdx.x;
  int e = topki[g];
  int p = off[e] + atomicAdd(&cursor[e], 1);
  tokmap[p] = g >> 3;
  wmap[p]   = topkw[g];
}

// ---------------- ragged MFMA GEMM (BM=256, BN=128, BK=32, 8 waves, 64KB LDS -> 2 blocks/CU) ----------------
// ROUND-6 STRUCTURE (frozen): dbuf gload_lds for A and B(f32), counted vmcnt(4),
// raw barriers, 2 blocks/CU cover each other's sync bubbles.
// GEMM==2 epilogue: atomicAdd into pre-zeroed out (routed: w*acc; shared: 0.5*acc)
// — replaces yslot+k_final (saves ~180MB traffic + a kernel).
template<int GEMM>
__global__ __launch_bounds__(512, 4) void k_gemm(
    const unsigned short* __restrict__ A1, const unsigned short* __restrict__ A2,
    const float* __restrict__ WE, const float* __restrict__ WS,
    const int* __restrict__ cnt, const int* __restrict__ off,
    const int* __restrict__ tokmap, const float* __restrict__ wmap,
    unsigned short* __restrict__ O1, unsigned short* __restrict__ O2,
    float* __restrict__ OD, const unsigned short* __restrict__ zpage)
{
  __shared__ __align__(16) char smem[65536]; // As[2][256][32]bf16 (32KB) | Bs[2][32][128]f32 (32KB); epilogue reuses as Hs
  const int bx = blockIdx.x, mt = blockIdx.y, nc = blockIdx.z;
  const bool sh = (bx >= 256);
  int e = bx, s = 0, M, Moff;
  if (!sh){ M = cnt[e]; Moff = mt*256; }
  else {
    int sidx = bx - 256;
    if (GEMM==1){ s = sidx>>3; Moff = (sidx&7)*512 + mt*256; }
    else        { s = 0;       Moff = sidx*1024 + mt*256; }
    M = 4096;
  }
  if (Moff >= M) return;
  const int tid=threadIdx.x, ln=tid&63, wv=tid>>6, wm=wv>>2, wn=wv&3, lrow=ln&15, lk=ln>>4;
  const int Ktot = (GEMM==1)?1024:(sh?512:256);
  const int ldB  = (GEMM==1)?512:1024;
  const float* Bp = (GEMM==1) ? (sh? WS + (size_t)s*524288 : WE + (size_t)e*524288)
                              : (sh? WS : WE + (size_t)e*262144);
  const int offe = sh? 0 : off[e];

  // per-thread A staging sources (2 gload_lds per wave per K-step, 16B/lane)
  const char* a_src[2];
  #pragma unroll
  for (int qi=0;qi<2;++qi){
    int row  = (wv*2+qi)*16 + (ln>>2);
    int grow = Moff + row;
    const unsigned short* p;
    if (GEMM==1){
      if (!sh) p = (grow < M)? A1 + (size_t)tokmap[offe+grow]*1024 : zpage;
      else     p = A1 + (size_t)grow*1024;
    } else {
      if (!sh) p = (grow < M)? A1 + ((size_t)offe+grow)*256 : zpage;
      else     p = A2 + (size_t)grow*512;
    }
    a_src[qi] = (const char*)p + (ln&3)*16;
  }
  // per-thread B staging sources (2 gload_lds per wave per K-step, 16B/lane; each instr = 2 k-rows).
  // Global col-granule pre-swizzled by (k>>3) so LDS fragment reads are conflict-free.
  const char* b_src[2];
  {
    int swz = ((wv>>1)&3)<<2;          // (k>>3)&3 <<2, uniform for this wave's 4 k-rows
    int cg  = (ln&31) ^ swz;           // 16B granule within 128-col row
    int c4  = cg*4;
    int gcol = (GEMM==1) ? ((c4<64)? nc*64 + c4 : 256 + nc*64 + (c4-64))
                         : (nc*128 + c4);
    int rbase = 4*wv + (ln>>5);
    #pragma unroll
    for (int q=0;q<2;++q)
      b_src[q] = (const char*)(Bp + (size_t)(rbase + 2*q)*ldB + gcol);
  }

  f32x4 acc[8][2] = {};

  auto stage = [&](int buf, int k0){
    #pragma unroll
    for (int qi=0;qi<2;++qi)
      __builtin_amdgcn_global_load_lds((const void*)(a_src[qi] + (size_t)k0*2),
          (void*)(smem + buf*16384 + (wv*2+qi)*1024), 16, 0, 0);
    #pragma unroll
    for (int q=0;q<2;++q)
      __builtin_amdgcn_global_load_lds((const void*)(b_src[q] + (size_t)k0*ldB*4),
          (void*)(smem + 32768 + buf*16384 + wv*2048 + q*1024), 16, 0, 0);
  };

  auto compute = [&](int buf){
    const short* as  = (const short*)(smem + buf*16384);
    const float* bs  = (const float*)(smem + 32768 + buf*16384);
    bf16x8 bv[2];
    #pragma unroll
    for (int ni=0;ni<2;++ni){
      int tc = (GEMM==1)? (ni*64 + wn*16 + lrow) : (wn*32 + ni*16 + lrow);
      int sloff = ((((tc>>2) ^ (lk<<2))<<2) | (tc&3));   // swizzled f32 index within row
      const float* colp = bs + (size_t)lk*8*128 + sloff;
      #pragma unroll
      for (int j=0;j<8;++j){
        unsigned u = __builtin_bit_cast(unsigned, colp[(size_t)j*128]);
        bv[ni][j] = (short)((u + 0x8000u) >> 16);        // round-half-up to bf16
      }
    }
    #pragma unroll
    for (int mi=0;mi<8;++mi){
      bf16x8 af = *(const bf16x8*)(as + (wm*128+mi*16+lrow)*32 + lk*8);
      acc[mi][0] = __builtin_amdgcn_mfma_f32_16x16x32_bf16(af, bv[0], acc[mi][0], 0,0,0);
      acc[mi][1] = __builtin_amdgcn_mfma_f32_16x16x32_bf16(af, bv[1], acc[mi][1], 0,0,0);
    }
  };

  stage(0, 0);
  const int ns = Ktot>>5;
  for (int t=0;t<ns;++t){
    int b = t&1;
    if (t+1<ns){
      stage(b^1, (t+1)<<5);                               // next tile's 4 loads issued FIRST
      asm volatile("s_waitcnt vmcnt(4)" ::: "memory");    // retire this tile's 4, keep next in flight
    } else {
      asm volatile("s_waitcnt vmcnt(0)" ::: "memory");
    }
    asm volatile("s_barrier" ::: "memory");               // all waves' DMA for buf b landed
    compute(b);
    asm volatile("s_barrier" ::: "memory");               // buf b free for next DMA
  }

  if (GEMM==1){ // silu(g)*u epilogue via LDS repack (Hs[256][72] bf16, padded stride)
    __syncthreads();
    unsigned short* Hs = (unsigned short*)smem;
    #pragma unroll
    for (int mi=0;mi<8;++mi){
      f32x4 g = acc[mi][0], u = acc[mi][1];
      #pragma unroll
      for (int r=0;r<4;++r){
        float gg = g[r];
        float hh = (gg / (1.f + __expf(-gg))) * u[r];
        int m = wm*128 + mi*16 + lk*4 + r;
        Hs[m*72 + wn*16 + lrow] = f2bf(hh);
      }
    }
    __syncthreads();
    #pragma unroll
    for (int i=0;i<4;++i){
      int id = tid + i*512, m = id>>3, c8 = id&7;
      int grow = Moff + m;
      if (grow < M){
        unsigned short* dst = (!sh) ? O1 + ((size_t)offe + grow)*256 + nc*64 + c8*8
                                    : O2 + (size_t)grow*512 + (size_t)s*256 + nc*64 + c8*8;
        *(f32x4*)dst = *(const f32x4*)(Hs + m*72 + c8*8);
      }
    }
  } else {
    if (sh){ // shared down: atomicAdd 0.5*acc into out
      #pragma unroll
      for (int mi=0;mi<8;++mi)
        #pragma unroll
        for (int ni=0;ni<2;++ni)
          #pragma unroll
          for (int r=0;r<4;++r){
            int m = Moff + wm*128 + mi*16 + lk*4 + r;
            int c = nc*128 + wn*32 + ni*16 + lrow;
            atomicAdd(&OD[(size_t)m*1024 + c], acc[mi][ni][r]*0.5f);
          }
    } else { // routed down: atomicAdd w*acc into out (tok/wgt preloaded to LDS)
      __syncthreads();
      int*   stok = (int*)smem;
      float* swgt = (float*)(smem + 1024);
      if (tid < 256){
        int gr = Moff + tid;
        if (gr < M){ stok[tid] = tokmap[offe+gr]; swgt[tid] = wmap[offe+gr]; }
      }
      __syncthreads();
      #pragma unroll
      for (int mi=0;mi<8;++mi)
        #pragma unroll
        for (int ni=0;ni<2;++ni)
          #pragma unroll
          for (int r=0;r<4;++r){
            int lr = wm*128 + mi*16 + lk*4 + r;
            if (Moff + lr < M){
              int c = nc*128 + wn*32 + ni*16 + lrow;
              atomicAdd(&OD[(size_t)stok[lr]*1024 + c], swgt[lr]*acc[mi][ni][r]);
            }
          }
    }
  }
}

extern "C" void kernel_launch(void* const* d_in, const int* in_sizes, int n_in,
                              void* d_out, int out_size, void* d_ws, size_t ws_size,
                              hipStream_t stream) {
  const float* x    = (const float*)d_in[0];
  const float* Wg   = (const float*)d_in[1];
  const float* Wgu  = (const float*)d_in[2];
  const float* Wd   = (const float*)d_in[3];
  const float* Wsgu = (const float*)d_in[4];
  const float* Wsd  = (const float*)d_in[5];
  float* out = (float*)d_out;

  char* W = (char*)d_ws; // ~97 MB
  unsigned short* xbf    = (unsigned short*)(W + WS_XBF);
  unsigned short* hsh    = (unsigned short*)(W + WS_HSH);
  unsigned short* hmid   = (unsigned short*)(W + WS_HMID);
  float* WgT     = (float*)(W + WS_WGT);
  int*   topki   = (int*)(W + WS_TOPKI);
  float* topkw   = (float*)(W + WS_TOPKW);
  int*   tokmap  = (int*)(W + WS_TOKMAP);
  float* wmap    = (float*)(W + WS_WMAP);
  int*   cnt     = (int*)(W + WS_CNT);
  int*   cursor  = (int*)(W + WS_CURSOR);
  unsigned short* zpage = (unsigned short*)(W + WS_ZERO);
  int*   off     = (int*)(W + WS_OFF);

  // zero cnt|cursor|zeropage (contiguous 6144 B); zero out (atomic target)
  hipMemsetAsync((void*)cnt, 0, 1024+1024+4096, stream);
  hipMemsetAsync((void*)out, 0, (size_t)out_size*4, stream);

  k_wgT    <<<dim3(16,4), 256, 0, stream>>>(Wg, WgT);
  k_router <<<512, 256, 0, stream>>>(x, WgT, xbf, topki, topkw, cnt);
  k_scan   <<<1, 256, 0, stream>>>(cnt, off);
  k_scatter<<<128, 256, 0, stream>>>(topki, topkw, off, cursor, tokmap, wmap);
  k_gemm<1><<<dim3(272,2,4), 512, 0, stream>>>(xbf, (const unsigned short*)nullptr,
        Wgu, Wsgu, cnt, off, tokmap, wmap, hmid, hsh, out, zpage);
  k_gemm<2><<<dim3(260,4,8), 512, 0, stream>>>(hmid, hsh,
        Wd, Wsd, cnt, off, tokmap, wmap, (unsigned short*)nullptr, (unsigned short*)nullptr, out, zpage);
}

// Round 10
// 354.171 us; speedup vs baseline: 1.1138x; 1.1138x over previous
//
#include <hip/hip_runtime.h>
#include <hip/hip_bf16.h>

// DeepseekV3 MoE: B=2,S=2048 -> n=4096 tokens, H=1024, I=256, E=256, K=8, G=8, TG=4, NS=2
// All inputs f32. Output f32 [4096][1024].

typedef __attribute__((ext_vector_type(4))) float  f32x4;
typedef __attribute__((ext_vector_type(8))) short  bf16x8;
typedef __attribute__((ext_vector_type(4))) short  bf16x4;
typedef __attribute__((ext_vector_type(4))) unsigned short u16x4;

#define DI static __device__ __forceinline__

DI unsigned short f2bf(float f){
  unsigned u = __builtin_bit_cast(unsigned, f);
  return (unsigned short)((u + 0x7FFFu + ((u>>16)&1u)) >> 16); // RNE (inputs finite)
}
DI float bf2f(unsigned short s){
  return __builtin_bit_cast(float, ((unsigned)s)<<16);
}

// ---------------- workspace layout (bytes) ----------------
#define WS_XBF      0u          /* 4096*1024 bf16 = 8,388,608 */
#define WS_HSH      8388608u    /* 4096*512 bf16  = 4,194,304 (shared h, concat s) */
#define WS_HMID     12582912u   /* 32768*256 bf16 = 16,777,216 */
#define WS_YSLOT    29360128u   /* 32768*1024 bf16= 67,108,864 */
#define WS_WGT      29360128u   /* WgT 1024*256 f32 = 1MB, OVERLAPS yslot (lifetime-disjoint) */
#define WS_TOPKI    96468992u   /* 4096*8 int */
#define WS_TOPKW    96600064u   /* 4096*8 f32 */
#define WS_TOKMAP   96731136u   /* 32768 int */
#define WS_SLOTMAP  96862208u   /* 32768 int */
#define WS_CNT      96993280u   /* 256 int */
#define WS_CURSOR   96994304u   /* 256 int */
#define WS_ZERO     96995328u   /* 4096 B zeros */
#define WS_OFF      96999424u   /* 257 int */

// ---------------- transpose Wg [256][1024] -> WgT [1024][256] ----------------
__global__ __launch_bounds__(256) void k_wgT(const float* __restrict__ Wg, float* __restrict__ WgT){
  __shared__ float t[64][65];
  const int tid = threadIdx.x;
  const int hx = blockIdx.x * 64;   // h tile (16 blocks)
  const int ex = blockIdx.y * 64;   // e tile (4 blocks)
  #pragma unroll
  for (int k=0;k<16;++k){
    int i = (tid>>6)*16 + k, j = tid&63;
    t[i][j] = Wg[(size_t)(ex+i)*1024 + hx + j];   // coalesced over j
  }
  __syncthreads();
  #pragma unroll
  for (int k=0;k<16;++k){
    int i = (tid>>6)*16 + k, j = tid&63;
    WgT[(size_t)(hx+i)*256 + ex + j] = t[j][i];   // coalesced over j
  }
}

// ---------------- router: logits via coalesced WgT + grouped top-k + softmax; folds x->bf16 ----------------
__global__ __launch_bounds__(256) void k_router(const float* __restrict__ x, const float* __restrict__ WgT,
                                                unsigned short* __restrict__ xbf,
                                                int* __restrict__ topki, float* __restrict__ topkw,
                                                int* __restrict__ cnt){
  __shared__ float xs[8][1024];   // 32KB
  __shared__ float lg[8][256];    // 8KB
  __shared__ float cv[8][32];
  __shared__ int   ce[8][32];
  const int tid = threadIdx.x;
  const int t0  = blockIdx.x * 8;
  { // load x tile + convert to bf16 (folded k_convert)
    const f32x4* xg = (const f32x4*)(x + (size_t)t0*1024);
    f32x4* xs4 = (f32x4*)&xs[0][0];
    u16x4* xb4 = (u16x4*)(xbf + (size_t)t0*1024);
    #pragma unroll
    for (int i=0;i<8;++i){
      f32x4 v = xg[tid + i*256];
      xs4[tid + i*256] = v;
      u16x4 p; p[0]=f2bf(v[0]); p[1]=f2bf(v[1]); p[2]=f2bf(v[2]); p[3]=f2bf(v[3]);
      xb4[tid + i*256] = p;
    }
  }
  __syncthreads();
  { // logits: expert e = tid; WgT reads coalesced (lane = expert); x broadcast from LDS
    f32x4 a4[8];
    #pragma unroll
    for (int t=0;t<8;++t) a4[t] = (f32x4){0.f,0.f,0.f,0.f};
    const float* wc = WgT + tid;
    for (int h4=0; h4<256; ++h4){
      float w0 = wc[(size_t)(h4*4+0)*256];
      float w1 = wc[(size_t)(h4*4+1)*256];
      float w2 = wc[(size_t)(h4*4+2)*256];
      float w3 = wc[(size_t)(h4*4+3)*256];
      f32x4 wv = (f32x4){w0,w1,w2,w3};
      #pragma unroll
      for (int t=0;t<8;++t){
        f32x4 xv = *((const f32x4*)&xs[t][0] + h4);
        a4[t] += wv * xv;
      }
    }
    #pragma unroll
    for (int t=0;t<8;++t){
      double d = ((double)a4[t][0] + (double)a4[t][1]) + ((double)a4[t][2] + (double)a4[t][3]);
      lg[t][tid] = (float)d;
    }
  }
  __syncthreads();
  if (tid < 64){ // per (token, group): top-4 of 32, ties -> lowest index
    int tok = tid>>3, grp = tid&7;
    unsigned mask = 0;
    for (int j=0;j<4;++j){
      float best = -3.4e38f; int bi = 0;
      for (int i=0;i<32;++i){
        float v = lg[tok][grp*32+i];
        if (!((mask>>i)&1u) && v > best){ best=v; bi=i; }
      }
      mask |= 1u<<bi;
      cv[tok][grp*4+j] = best; ce[tok][grp*4+j] = grp*32+bi;
    }
  }
  __syncthreads();
  if (tid < 8){ // per token: top-8 of 32 candidates + softmax
    int tok = tid; unsigned mask=0;
    float vals[8]; int es[8];
    #pragma unroll
    for (int k=0;k<8;++k){
      float best=-3.4e38f; int bp=0;
      for (int p=0;p<32;++p){
        float v = cv[tok][p];
        if (!((mask>>p)&1u) && v > best){ best=v; bp=p; }
      }
      mask|=1u<<bp; vals[k]=best; es[k]=ce[tok][bp];
    }
    float m = vals[0], s=0.f, w[8];
    #pragma unroll
    for (int k=0;k<8;++k){ w[k]=expf(vals[k]-m); s+=w[k]; }
    float inv = 1.f/s;
    #pragma unroll
    for (int k=0;k<8;++k){
      int g=(t0+tok)*8+k;
      topki[g]=es[k]; topkw[g]=w[k]*inv;
      atomicAdd(&cnt[es[k]],1);
    }
  }
}

// ---------------- exclusive scan of 256 counts ----------------
__global__ void k_scan(const int* __restrict__ cnt, int* __restrict__ off){
  __shared__ int s[256];
  int tid=threadIdx.x;
  s[tid]=cnt[tid]; __syncthreads();
  for (int d=1; d<256; d<<=1){
    int v = (tid>=d)? s[tid-d] : 0; __syncthreads();
    s[tid]+=v; __syncthreads();
  }
  off[tid+1]=s[tid]; if(tid==0) off[0]=0;
}

// ---------------- scatter tokens into per-expert slots ----------------
__global__ void k_scatter(const int* __restrict__ topki, const int* __restrict__ off,
                          int* __restrict__ cursor, int* __restrict__ tokmap, int* __restrict__ slotmap){
  int g = blockIdx.x*256 + threadIdx.x;
  int e = topki[g];
  int p = off[e] + atomicAdd(&cursor[e], 1);
  tokmap[p] = g >> 3;
  slotmap[g] = p;
}

// ---------------- ragged MFMA GEMM (BM=256, BN=128, BK=32, 8 waves, 64KB LDS -> 2 blocks/CU) ----------------
// ROUND-6 STRUCTURE (frozen): dbuf gload_lds A+B(f32), counted vmcnt(4), raw barriers,
// 2 blocks/CU. NEW: wave-uniform row-skip — strips of 16 rows fully beyond M skip
// af-load + MFMA (acc stays 0 == zpage result); staging kept so vmcnt stays exact.
// Routed blocks (cnt~128 vs BM=256) halve their compute-phase critical path.
template<int GEMM>
__global__ __launch_bounds__(512, 4) void k_gemm(
    const unsigned short* __restrict__ A1, const unsigned short* __restrict__ A2,
    const float* __restrict__ WE, const float* __restrict__ WS,
    const int* __restrict__ cnt, const int* __restrict__ off,
    const int* __restrict__ tokmap,
    unsigned short* __restrict__ O1, unsigned short* __restrict__ O2,
    float* __restrict__ OD, const unsigned short* __restrict__ zpage)
{
  __shared__ __align__(16) char smem[65536]; // As[2][256][32]bf16 (32KB) | Bs[2][32][128]f32 (32KB); epilogue reuses as Hs
  const int bx = blockIdx.x, mt = blockIdx.y, nc = blockIdx.z;
  const bool sh = (bx >= 256);
  int e = bx, s = 0, M, Moff;
  if (!sh){ M = cnt[e]; Moff = mt*256; }
  else {
    int sidx = bx - 256;
    if (GEMM==1){ s = sidx>>3; Moff = (sidx&7)*512 + mt*256; }
    else        { s = 0;       Moff = sidx*512 + mt*256; }   // sidx 0..7, mt 0..1 -> 4096
    M = 4096;
  }
  if (Moff >= M) return;
  const int tid=threadIdx.x, ln=tid&63, wv=tid>>6, wm=wv>>2, wn=wv&3, lrow=ln&15, lk=ln>>4;
  const int Ktot = (GEMM==1)?1024:(sh?512:256);
  const int ldB  = (GEMM==1)?512:1024;
  const float* Bp = (GEMM==1) ? (sh? WS + (size_t)s*524288 : WE + (size_t)e*524288)
                              : (sh? WS : WE + (size_t)e*262144);
  const int offe = sh? 0 : off[e];

  // per-thread A staging sources (2 gload_lds per wave per K-step, 16B/lane)
  const char* a_src[2];
  #pragma unroll
  for (int qi=0;qi<2;++qi){
    int row  = (wv*2+qi)*16 + (ln>>2);
    int grow = Moff + row;
    const unsigned short* p;
    if (GEMM==1){
      if (!sh) p = (grow < M)? A1 + (size_t)tokmap[offe+grow]*1024 : zpage;
      else     p = A1 + (size_t)grow*1024;
    } else {
      if (!sh) p = (grow < M)? A1 + ((size_t)offe+grow)*256 : zpage;
      else     p = A2 + (size_t)grow*512;
    }
    a_src[qi] = (const char*)p + (ln&3)*16;
  }
  // per-thread B staging sources (2 gload_lds per wave per K-step, 16B/lane; each instr = 2 k-rows).
  // Global col-granule pre-swizzled by (k>>3) so LDS fragment reads are conflict-free.
  const char* b_src[2];
  {
    int swz = ((wv>>1)&3)<<2;          // (k>>3)&3 <<2, uniform for this wave's 4 k-rows
    int cg  = (ln&31) ^ swz;           // 16B granule within 128-col row
    int c4  = cg*4;
    int gcol = (GEMM==1) ? ((c4<64)? nc*64 + c4 : 256 + nc*64 + (c4-64))
                         : (nc*128 + c4);
    int rbase = 4*wv + (ln>>5);
    #pragma unroll
    for (int q=0;q<2;++q)
      b_src[q] = (const char*)(Bp + (size_t)(rbase + 2*q)*ldB + gcol);
  }

  f32x4 acc[8][2] = {};

  auto stage = [&](int buf, int k0){
    #pragma unroll
    for (int qi=0;qi<2;++qi)
      __builtin_amdgcn_global_load_lds((const void*)(a_src[qi] + (size_t)k0*2),
          (void*)(smem + buf*16384 + (wv*2+qi)*1024), 16, 0, 0);
    #pragma unroll
    for (int q=0;q<2;++q)
      __builtin_amdgcn_global_load_lds((const void*)(b_src[q] + (size_t)k0*ldB*4),
          (void*)(smem + 32768 + buf*16384 + wv*2048 + q*1024), 16, 0, 0);
  };

  auto compute = [&](int buf){
    const short* as  = (const short*)(smem + buf*16384);
    const float* bs  = (const float*)(smem + 32768 + buf*16384);
    bf16x8 bv[2];
    #pragma unroll
    for (int ni=0;ni<2;++ni){
      int tc = (GEMM==1)? (ni*64 + wn*16 + lrow) : (wn*32 + ni*16 + lrow);
      int sloff = ((((tc>>2) ^ (lk<<2))<<2) | (tc&3));   // swizzled f32 index within row
      const float* colp = bs + (size_t)lk*8*128 + sloff;
      #pragma unroll
      for (int j=0;j<8;++j){
        unsigned u = __builtin_bit_cast(unsigned, colp[(size_t)j*128]);
        bv[ni][j] = (short)((u + 0x8000u) >> 16);        // round-half-up to bf16
      }
    }
    #pragma unroll
    for (int mi=0;mi<8;++mi){
      if (Moff + wm*128 + mi*16 < M){                    // wave-uniform row-skip
        bf16x8 af = *(const bf16x8*)(as + (wm*128+mi*16+lrow)*32 + lk*8);
        acc[mi][0] = __builtin_amdgcn_mfma_f32_16x16x32_bf16(af, bv[0], acc[mi][0], 0,0,0);
        acc[mi][1] = __builtin_amdgcn_mfma_f32_16x16x32_bf16(af, bv[1], acc[mi][1], 0,0,0);
      }
    }
  };

  stage(0, 0);
  const int ns = Ktot>>5;
  for (int t=0;t<ns;++t){
    int b = t&1;
    if (t+1<ns){
      stage(b^1, (t+1)<<5);                               // next tile's 4 loads issued FIRST
      asm volatile("s_waitcnt vmcnt(4)" ::: "memory");    // retire this tile's 4, keep next in flight
    } else {
      asm volatile("s_waitcnt vmcnt(0)" ::: "memory");
    }
    asm volatile("s_barrier" ::: "memory");               // all waves' DMA for buf b landed
    compute(b);
    asm volatile("s_barrier" ::: "memory");               // buf b free for next DMA
  }

  if (GEMM==1){ // silu(g)*u epilogue via LDS repack (Hs[256][72] bf16, padded stride)
    __syncthreads();
    unsigned short* Hs = (unsigned short*)smem;
    #pragma unroll
    for (int mi=0;mi<8;++mi){
      f32x4 g = acc[mi][0], u = acc[mi][1];
      #pragma unroll
      for (int r=0;r<4;++r){
        float gg = g[r];
        float hh = (gg / (1.f + __expf(-gg))) * u[r];
        int m = wm*128 + mi*16 + lk*4 + r;
        Hs[m*72 + wn*16 + lrow] = f2bf(hh);
      }
    }
    __syncthreads();
    #pragma unroll
    for (int i=0;i<4;++i){
      int id = tid + i*512, m = id>>3, c8 = id&7;
      int grow = Moff + m;
      if (grow < M){
        unsigned short* dst = (!sh) ? O1 + ((size_t)offe + grow)*256 + nc*64 + c8*8
                                    : O2 + (size_t)grow*512 + (size_t)s*256 + nc*64 + c8*8;
        *(f32x4*)dst = *(const f32x4*)(Hs + m*72 + c8*8);
      }
    }
  } else {
    if (sh){ // (y0+y1)/2 straight to d_out (f32, plain stores)
      #pragma unroll
      for (int mi=0;mi<8;++mi)
        #pragma unroll
        for (int ni=0;ni<2;++ni)
          #pragma unroll
          for (int r=0;r<4;++r){
            int m = Moff + wm*128 + mi*16 + lk*4 + r;
            int c = nc*128 + wn*32 + ni*16 + lrow;
            OD[(size_t)m*1024 + c] = acc[mi][ni][r]*0.5f;
          }
    } else { // yslot bf16 via Hs[256][128] (single pass, all waves)
      __syncthreads();
      unsigned short* Hs = (unsigned short*)smem;
      #pragma unroll
      for (int mi=0;mi<8;++mi)
        #pragma unroll
        for (int ni=0;ni<2;++ni)
          #pragma unroll
          for (int r=0;r<4;++r){
            int m = wm*128 + mi*16 + lk*4 + r;
            int c = wn*32 + ni*16 + lrow;
            Hs[m*128 + c] = f2bf(acc[mi][ni][r]);
          }
      __syncthreads();
      #pragma unroll
      for (int i=0;i<8;++i){
        int id = tid + i*512, m = id>>4, c8 = id&15;
        int grow = Moff + m;
        if (grow < M){
          unsigned short* dst = O1 + ((size_t)offe+grow)*1024 + nc*128 + c8*8;
          *(f32x4*)dst = *(const f32x4*)(Hs + m*128 + c8*8);
        }
      }
    }
  }
}

// ---------------- final gather: out = shared + sum_k w * yslot ----------------
__global__ void k_final(float* __restrict__ out, const unsigned short* __restrict__ yslot,
                        const int* __restrict__ slotmap, const float* __restrict__ topkw){
  __shared__ int sp[8]; __shared__ float sw[8];
  int t = blockIdx.x, tid = threadIdx.x;
  if (tid<8){ sp[tid]=slotmap[t*8+tid]; sw[tid]=topkw[t*8+tid]; }
  __syncthreads();
  int c = tid*4;
  f32x4 o = *(f32x4*)(out + (size_t)t*1024 + c);
  #pragma unroll
  for (int k=0;k<8;++k){
    u16x4 y = *(const u16x4*)(yslot + (size_t)sp[k]*1024 + c);
    float w = sw[k];
    o[0] += w*bf2f(y[0]); o[1] += w*bf2f(y[1]); o[2] += w*bf2f(y[2]); o[3] += w*bf2f(y[3]);
  }
  *(f32x4*)(out + (size_t)t*1024 + c) = o;
}

extern "C" void kernel_launch(void* const* d_in, const int* in_sizes, int n_in,
                              void* d_out, int out_size, void* d_ws, size_t ws_size,
                              hipStream_t stream) {
  const float* x    = (const float*)d_in[0];
  const float* Wg   = (const float*)d_in[1];
  const float* Wgu  = (const float*)d_in[2];
  const float* Wd   = (const float*)d_in[3];
  const float* Wsgu = (const float*)d_in[4];
  const float* Wsd  = (const float*)d_in[5];
  float* out = (float*)d_out;

  char* W = (char*)d_ws; // ~97 MB
  unsigned short* xbf    = (unsigned short*)(W + WS_XBF);
  unsigned short* hsh    = (unsigned short*)(W + WS_HSH);
  unsigned short* hmid   = (unsigned short*)(W + WS_HMID);
  unsigned short* yslot  = (unsigned short*)(W + WS_YSLOT);
  float* WgT     = (float*)(W + WS_WGT);   // overlaps yslot (disjoint lifetime)
  int*   topki   = (int*)(W + WS_TOPKI);
  float* topkw   = (float*)(W + WS_TOPKW);
  int*   tokmap  = (int*)(W + WS_TOKMAP);
  int*   slotmap = (int*)(W + WS_SLOTMAP);
  int*   cnt     = (int*)(W + WS_CNT);
  int*   cursor  = (int*)(W + WS_CURSOR);
  unsigned short* zpage = (unsigned short*)(W + WS_ZERO);
  int*   off     = (int*)(W + WS_OFF);

  // zero cnt|cursor|zeropage (contiguous 6144 B)
  hipMemsetAsync((void*)cnt, 0, 1024+1024+4096, stream);

  k_wgT    <<<dim3(16,4), 256, 0, stream>>>(Wg, WgT);
  k_router <<<512, 256, 0, stream>>>(x, WgT, xbf, topki, topkw, cnt);
  k_scan   <<<1, 256, 0, stream>>>(cnt, off);
  k_scatter<<<128, 256, 0, stream>>>(topki, off, cursor, tokmap, slotmap);
  k_gemm<1><<<dim3(272,2,4), 512, 0, stream>>>(xbf, (const unsigned short*)nullptr,
        Wgu, Wsgu, cnt, off, tokmap, hmid, hsh, out, zpage);
  k_gemm<2><<<dim3(264,2,8), 512, 0, stream>>>(hmid, hsh,
        Wd, Wsd, cnt, off, tokmap, yslot, (unsigned short*)nullptr, out, zpage);
  k_final <<<4096, 256, 0, stream>>>(out, yslot, slotmap, topkw);
}